// Round 3
// baseline (256.957 us; speedup 1.0000x reference)
//
#include <hip/hip_runtime.h>

// Muskingum-Cunge routing, MI355X — single outlet chain (out = Q[15, 2047]).
// 16-lane systolic pipeline, lane = level, DPP row_shr:1 handoff.
//
// Round-3 restructure: carry state as FRACTION (nh, dd) with Qnew = nh/dd.
//   Qref = max(0.5*(up + lat + nh/dd), QMIN) is formed multiplied by dd*up_d:
//     TT2 = up_d*(lat*dd + nh) + up_n*dd ;  TTc = max(TT2, 2*QMIN*dd*up_d)
//     log2(Qref) = log2(TTc) - (1 + log2(dd) + log2(up_d))
//   so v_rcp leaves the critical chain (rcp/log2(dd) have a full step of slack;
//   they only feed the value-form P1/P2/hsI terms which join late).
//   Kh = A*Qref^-0.2, Ku = B*Qref^0.1, Kmin = min(Ku,Kh) (min in log domain),
//   num = Kh*P1 + Kmin*P2 + HDT*sI, denom' = HDT + Kh + Kmin, nh' = max(num,0).
// Chain: dpp/fma/max(~23) -> log(28) -> fma -> exp2(28) -> min/add/fma -> max ≈ 101 cyc.

#define T_STEPS 730
#define NROWS   (T_STEPS + 14)   // 4 leading zero rows + 730 data + 10 zero pad
#define HDT     10800.0f         // 0.5 * (86400/4)
#define QMIN2   2e-3f            // 2 * Q_MIN

__device__ __forceinline__ float dpp0(float x) {
    // lane i <- lane i-1 within rows of 16; bound_ctrl=1 => lane 0 gets 0
    return __int_as_float(__builtin_amdgcn_mov_dpp(__float_as_int(x), 0x111, 0xF, 0xF, true));
}

__global__ __launch_bounds__(1024, 1)
void mc_route(const float* __restrict__ inflow,
              const float* __restrict__ log_n,
              const float* __restrict__ dxs,
              const float* __restrict__ slopes,
              float* __restrict__ out)
{
    __shared__ float lat_s[NROWS * 16];

    const int tid = threadIdx.x;
    for (int i = tid; i < NROWS * 16; i += 1024) {
        int t = (i >> 4) - 4;
        float v = 0.0f;
        if ((unsigned)t < (unsigned)T_STEPS)
            v = inflow[t * 32768 + (i & 15) * 2048 + 2047];
        lat_s[i] = v;
    }
    __syncthreads();
    if (tid >= 16) return;       // only the 16 pipeline lanes continue

    const int lane = tid;
    const int g    = lane * 2048 + 2047;

    const float nman  = expf(log_n[g]);
    const float S     = slopes[g];
    const float dx    = dxs[g];
    // 1/c = invA2 * Qref^-0.2 ; invA2 = n / ((5/3)*0.27^(2/3)*sqrt(S))
    const float invA2 = 1.4362848f * nman / __builtin_amdgcn_sqrtf(S);
    const float A     = 0.5f * dx * invA2;                 // Kh = A*Qref^-0.2
    const float B     = 0.5f * invA2 * invA2 / (7.2f * S); // Ku = B*Qref^0.1
    const float lKh1  = log2f(A) + 0.2f;   // folds the "+1" of the 0.5 factor
    const float lKu1  = log2f(B) - 0.1f;
    const bool  isl0  = (lane == 0);

    // rotating LDS pointers (buffer j refilled at steps k===j mod 4, for k+4)
    const float* p0 = lat_s + (5 + ((0 - lane) >> 2)) * 16 + lane;
    const float* p1 = lat_s + (5 + ((1 - lane) >> 2)) * 16 + lane;
    const float* p2 = lat_s + (5 + ((2 - lane) >> 2)) * 16 + lane;
    const float* p3 = lat_s + (5 + ((3 - lane) >> 2)) * 16 + lane;

    float b0 = lat_s[(4 + ((0 - lane) >> 2)) * 16 + lane];
    float b1 = lat_s[(4 + ((1 - lane) >> 2)) * 16 + lane];
    float b2 = lat_s[(4 + ((2 - lane) >> 2)) * 16 + lane];
    float b3 = lat_s[(4 + ((3 - lane) >> 2)) * 16 + lane];

    // State: nh = max(num,0), dd = denom  (Qnew = nh/dd), Iold = previous inflow.
    float nh = 0.0f, dd = HDT, Iold = 0.0f;

#define STEP(BUF, LD_EXPR, STCODE) do {                                   \
    const float lat  = BUF;                                               \
    BUF = (LD_EXPR);                     /* prefetch for k+4 */           \
    /* slack ops: value-form of previous step's Qnew */                   \
    const float LDd  = __builtin_amdgcn_logf(dd);   /* log2(dd) */        \
    const float rdd  = __builtin_amdgcn_rcpf(dd);                         \
    const float Qold = nh * rdd;         /* own Qnew at step k-1 */       \
    /* neighbor handoffs (values of step k-1) */                          \
    const float up_n  = dpp0(nh);                                         \
    const float up_d0 = dpp0(dd);                                         \
    const float up_d  = isl0 ? 1.0f : up_d0;                              \
    const float up_L  = dpp0(LDd);       /* lane0 -> 0 == log2(1) */      \
    const float up_Q  = dpp0(Qold);      /* upstream discharge value */   \
    STCODE                                                                \
    /* fraction-form Qref (no division on chain) */                       \
    const float inner = fmaf(lat, dd, nh);                                \
    const float bb    = up_n * dd;                                        \
    const float TT2   = fmaf(up_d, inner, bb);                            \
    const float qq    = (QMIN2 * dd) * up_d;                              \
    const float TTc   = fmaxf(TT2, qq);                                   \
    const float lgn   = __builtin_amdgcn_logf(TTc);                       \
    const float s     = LDd + up_L;      /* log2(dd*up_d), slack path */  \
    const float cKh   = fmaf(0.2f, s, lKh1);                              \
    const float cKu   = fmaf(-0.1f, s, lKu1);                             \
    const float tKh   = fmaf(-0.2f, lgn, cKh);                            \
    const float tKu   = fmaf(0.1f, lgn, cKu);                             \
    const float tmn   = fminf(tKu, tKh); /* min in log domain (exact) */  \
    const float Kh    = __builtin_amdgcn_exp2f(tKh);                      \
    const float Kmin  = __builtin_amdgcn_exp2f(tmn);                      \
    /* value-form linear terms (all off the trans chain) */               \
    const float Inew  = up_Q + lat;                                       \
    const float Siq   = Iold + Qold;                                      \
    const float Dif   = Iold - Qold;                                      \
    const float P1    = Siq - Inew;                                       \
    const float P2    = Inew - Dif;                                       \
    const float hsI   = fmaf(HDT, Inew, HDT * Dif);                       \
    const float num1  = fmaf(Kh, P1, hsI);                                \
    const float num2  = fmaf(Kmin, P2, num1);                             \
    nh = fmaxf(num2, 0.0f);                                               \
    dd = (HDT + Kh) + Kmin;                                               \
    Iold = Inew;                                                          \
} while (0);

    // ---- Prologue: k = 0..15 (no valid stores; Qold outputs start at k=19) ----
    STEP(b0, p0[0],  {}) STEP(b1, p1[0],  {}) STEP(b2, p2[0],  {}) STEP(b3, p3[0],  {})
    STEP(b0, p0[16], {}) STEP(b1, p1[16], {}) STEP(b2, p2[16], {}) STEP(b3, p3[16], {})
    STEP(b0, p0[32], {}) STEP(b1, p1[32], {}) STEP(b2, p2[32], {}) STEP(b3, p3[32], {})
    STEP(b0, p0[48], {}) STEP(b1, p1[48], {}) STEP(b2, p2[48], {}) STEP(b3, p3[48], {})
    p0 += 64; p1 += 64; p2 += 64; p3 += 64;

    // ---- Main: 182 blocks x 16 steps (k = 16..2927); Qold stored at k%4==3 ----
    float* outp = out;
    #pragma unroll 1
    for (int blk = 0; blk < 182; ++blk) {
        float4 st;
        STEP(b0, p0[0],  {}) STEP(b1, p1[0],  {}) STEP(b2, p2[0],  {}) STEP(b3, p3[0],  st.x = Qold;)
        STEP(b0, p0[16], {}) STEP(b1, p1[16], {}) STEP(b2, p2[16], {}) STEP(b3, p3[16], st.y = Qold;)
        STEP(b0, p0[32], {}) STEP(b1, p1[32], {}) STEP(b2, p2[32], {}) STEP(b3, p3[32], st.z = Qold;)
        STEP(b0, p0[48], {}) STEP(b1, p1[48], {}) STEP(b2, p2[48], {}) STEP(b3, p3[48], st.w = Qold;)
        if (lane == 15) *reinterpret_cast<float4*>(outp) = st;
        outp += 4;
        p0 += 64; p1 += 64; p2 += 64; p3 += 64;
    }

    // ---- Epilogue: k = 2928..2935; stores idx 728 (k=2931), 729 (k=2935) ----
    {
        float2 st2;
        STEP(b0, p0[0],  {}) STEP(b1, p1[0],  {}) STEP(b2, p2[0],  {}) STEP(b3, p3[0],  st2.x = Qold;)
        STEP(b0, p0[16], {}) STEP(b1, p1[16], {}) STEP(b2, p2[16], {}) STEP(b3, p3[16], st2.y = Qold;)
        if (lane == 15) *reinterpret_cast<float2*>(out + 728) = st2;
    }
#undef STEP
}

extern "C" void kernel_launch(void* const* d_in, const int* in_sizes, int n_in,
                              void* d_out, int out_size, void* d_ws, size_t ws_size,
                              hipStream_t stream) {
    const float* inflow = (const float*)d_in[0];
    const float* log_n  = (const float*)d_in[1];
    const float* dxs    = (const float*)d_in[2];
    const float* slopes = (const float*)d_in[3];
    float* out = (float*)d_out;
    mc_route<<<1, 1024, 0, stream>>>(inflow, log_n, dxs, slopes, out);
}

// Round 4
// 235.893 us; speedup vs baseline: 1.0893x; 1.0893x over previous
//
#include <hip/hip_runtime.h>

// Muskingum-Cunge routing, MI355X — single outlet chain (out = Q[15, 2047]).
// 16-lane systolic pipeline, lane = level, DPP row_shr:1 handoff.
//
// Fraction-carry v2: state (nh, dd), Qnew = nh/dd. Exactly 2 DPPs per step
// (nh, dd), lane-0 identity via update_dpp old-operand (no cndmask).
// Value-form terms (Qold, upQ) recovered via rcp on the slack path.
//   TT2 = up_d*(lat*dd + nh) + up_n*dd ; TTc = max(TT2, QMIN2*dd*up_d)
//   log2(Qref) = log2(TTc) - 1 - log2(dd*up_d)   [one log of the product]
//   tKh = -0.2*lgn + cKh, tKu = 0.1*lgn + cKu, Kmin = exp2(min(tKu,tKh))
//   num = Kh*P1 + Kmin*P2 + HDT*sI ; nh' = max(num,0); dd' = HDT+Kh+Kmin
// Cycle: dpp(20) fma(12) max(6) log(28) fma(6) min(6) exp2(28) adds(12) ~ 118.

#define T_STEPS 730
#define NROWS   (T_STEPS + 14)   // 4 leading zero rows + 730 data + 10 zero pad
#define HDT     10800.0f         // 0.5 * (86400/4)
#define QMIN2   2e-3f            // 2 * Q_MIN

__device__ __forceinline__ float dpp_sh1_zero(float x) {
    // lane i <- lane i-1 in rows of 16; row-start lanes get 0
    return __int_as_float(__builtin_amdgcn_update_dpp(
        0, __float_as_int(x), 0x111, 0xF, 0xF, true));
}
__device__ __forceinline__ float dpp_sh1_one(float x) {
    // lane i <- lane i-1 in rows of 16; row-start lanes keep old (=1.0f)
    return __int_as_float(__builtin_amdgcn_update_dpp(
        __float_as_int(1.0f), __float_as_int(x), 0x111, 0xF, 0xF, false));
}

__global__ __launch_bounds__(1024, 1)
void mc_route(const float* __restrict__ inflow,
              const float* __restrict__ log_n,
              const float* __restrict__ dxs,
              const float* __restrict__ slopes,
              float* __restrict__ out)
{
    __shared__ float lat_s[NROWS * 16];

    const int tid = threadIdx.x;
    for (int i = tid; i < NROWS * 16; i += 1024) {
        int t = (i >> 4) - 4;
        float v = 0.0f;
        if ((unsigned)t < (unsigned)T_STEPS)
            v = inflow[t * 32768 + (i & 15) * 2048 + 2047];
        lat_s[i] = v;
    }
    __syncthreads();
    if (tid >= 64) return;       // wave 0 runs the pipeline (64 lanes alive, as r2)

    const int lane = tid;
    const int lvl  = lane < 15 ? lane : 15;   // lanes 16..63 ride along (benign)
    const int g    = lvl * 2048 + 2047;

    const float nman  = expf(log_n[g]);
    const float S     = slopes[g];
    const float dx    = dxs[g];
    const float invA2 = 1.4362848f * nman / __builtin_amdgcn_sqrtf(S);
    const float A     = 0.5f * dx * invA2;                 // Kh = A*Qref^-0.2
    const float B     = 0.5f * invA2 * invA2 / (7.2f * S); // Ku = B*Qref^0.1
    const float lKh1  = log2f(A) + 0.2f;
    const float lKu1  = log2f(B) - 0.1f;

    // rotating LDS pointers (buffer j refilled at steps k===j mod 4, for k+4)
    const float* p0 = lat_s + (5 + ((0 - lvl) >> 2)) * 16 + lvl;
    const float* p1 = lat_s + (5 + ((1 - lvl) >> 2)) * 16 + lvl;
    const float* p2 = lat_s + (5 + ((2 - lvl) >> 2)) * 16 + lvl;
    const float* p3 = lat_s + (5 + ((3 - lvl) >> 2)) * 16 + lvl;

    float b0 = lat_s[(4 + ((0 - lvl) >> 2)) * 16 + lvl];
    float b1 = lat_s[(4 + ((1 - lvl) >> 2)) * 16 + lvl];
    float b2 = lat_s[(4 + ((2 - lvl) >> 2)) * 16 + lvl];
    float b3 = lat_s[(4 + ((3 - lvl) >> 2)) * 16 + lvl];

    float nh = 0.0f, dd = HDT, Iold = 0.0f;

#define STEP(BUF, LD_EXPR, STCODE) do {                                   \
    const float lat  = BUF;                                               \
    BUF = (LD_EXPR);                     /* prefetch for k+4 */           \
    /* 2 DPPs, sources stable since end of previous step */               \
    const float up_n = dpp_sh1_zero(nh);                                  \
    const float up_d = dpp_sh1_one(dd);                                   \
    /* main chain: fraction-form Qref */                                  \
    const float inner= fmaf(lat, dd, nh);                                 \
    const float bb   = up_n * dd;                                         \
    const float prod = dd * up_d;                                         \
    const float TT2  = fmaf(up_d, inner, bb);                             \
    const float qq   = QMIN2 * prod;                                      \
    const float TTc  = fmaxf(TT2, qq);                                    \
    const float lprod= __builtin_amdgcn_logf(prod);  /* slack */          \
    const float lgn  = __builtin_amdgcn_logf(TTc);   /* chain */          \
    /* slack: value-form of previous step (idle trans pipe) */            \
    const float rdd  = __builtin_amdgcn_rcpf(dd);                         \
    const float urd  = __builtin_amdgcn_rcpf(up_d);                       \
    const float Qold = nh * rdd;                                          \
    const float upQ  = up_n * urd;                                        \
    const float Inew = upQ + lat;                                         \
    const float Dif  = Iold - Qold;                                       \
    const float Siq  = Iold + Qold;                                       \
    const float P1   = Siq - Inew;                                        \
    const float P2   = Inew - Dif;                                        \
    const float hsI  = fmaf(HDT, Inew, HDT * Dif);                        \
    const float cKh  = fmaf(0.2f, lprod, lKh1);                           \
    const float cKu  = fmaf(-0.1f, lprod, lKu1);                          \
    const float tKh  = fmaf(-0.2f, lgn, cKh);                             \
    const float tKu  = fmaf(0.1f, lgn, cKu);                              \
    const float tmn  = fminf(tKu, tKh);  /* min in log domain (exact) */  \
    const float Kh   = __builtin_amdgcn_exp2f(tKh);                       \
    const float Kmn  = __builtin_amdgcn_exp2f(tmn);                       \
    const float num1 = fmaf(Kh, P1, hsI);                                 \
    const float num2 = fmaf(Kmn, P2, num1);                               \
    STCODE                                                                \
    dd = (HDT + Kh) + Kmn;                                                \
    nh = fmaxf(num2, 0.0f);                                               \
    Iold = Inew;                                                          \
} while (0);

    // ---- Prologue: k = 0..15 (no valid stores; outputs start at k=19) ----
    STEP(b0, p0[0],  {}) STEP(b1, p1[0],  {}) STEP(b2, p2[0],  {}) STEP(b3, p3[0],  {})
    STEP(b0, p0[16], {}) STEP(b1, p1[16], {}) STEP(b2, p2[16], {}) STEP(b3, p3[16], {})
    STEP(b0, p0[32], {}) STEP(b1, p1[32], {}) STEP(b2, p2[32], {}) STEP(b3, p3[32], {})
    STEP(b0, p0[48], {}) STEP(b1, p1[48], {}) STEP(b2, p2[48], {}) STEP(b3, p3[48], {})
    p0 += 64; p1 += 64; p2 += 64; p3 += 64;

    // ---- Main: 182 blocks x 16 steps (k = 16..2927); Qold stored at k%4==3 ----
    float* outp = out;
    #pragma unroll 1
    for (int blk = 0; blk < 182; ++blk) {
        float4 st;
        STEP(b0, p0[0],  {}) STEP(b1, p1[0],  {}) STEP(b2, p2[0],  {}) STEP(b3, p3[0],  st.x = Qold;)
        STEP(b0, p0[16], {}) STEP(b1, p1[16], {}) STEP(b2, p2[16], {}) STEP(b3, p3[16], st.y = Qold;)
        STEP(b0, p0[32], {}) STEP(b1, p1[32], {}) STEP(b2, p2[32], {}) STEP(b3, p3[32], st.z = Qold;)
        STEP(b0, p0[48], {}) STEP(b1, p1[48], {}) STEP(b2, p2[48], {}) STEP(b3, p3[48], st.w = Qold;)
        if (lane == 15) *reinterpret_cast<float4*>(outp) = st;
        outp += 4;
        p0 += 64; p1 += 64; p2 += 64; p3 += 64;
    }

    // ---- Epilogue: k = 2928..2935; stores idx 728 (k=2931), 729 (k=2935) ----
    {
        float2 st2;
        STEP(b0, p0[0],  {}) STEP(b1, p1[0],  {}) STEP(b2, p2[0],  {}) STEP(b3, p3[0],  st2.x = Qold;)
        STEP(b0, p0[16], {}) STEP(b1, p1[16], {}) STEP(b2, p2[16], {}) STEP(b3, p3[16], st2.y = Qold;)
        if (lane == 15) *reinterpret_cast<float2*>(out + 728) = st2;
    }
#undef STEP
}

extern "C" void kernel_launch(void* const* d_in, const int* in_sizes, int n_in,
                              void* d_out, int out_size, void* d_ws, size_t ws_size,
                              hipStream_t stream) {
    const float* inflow = (const float*)d_in[0];
    const float* log_n  = (const float*)d_in[1];
    const float* dxs    = (const float*)d_in[2];
    const float* slopes = (const float*)d_in[3];
    float* out = (float*)d_out;
    mc_route<<<1, 1024, 0, stream>>>(inflow, log_n, dxs, slopes, out);
}